// Round 1
// baseline (144.946 us; speedup 1.0000x reference)
//
#include <hip/hip_runtime.h>
#include <math.h>

#define BS    128
#define NE    512
#define F     6
#define NH    4
#define DPH   4
#define NEMBD 16

#define CH    8
#define CPAD  65   // float4 stride per chunk; 8 broadcast addrs/wave, conflict-free (r2-r8)

#if __has_builtin(__builtin_amdgcn_exp2f)
#define EXP2(x) __builtin_amdgcn_exp2f(x)
#else
#define EXP2(x) exp2f(x)
#endif

typedef float v2f __attribute__((ext_vector_type(2)));

// Per-batch arrival counter for the fused epilogue. Zero-initialized at module
// load; the epilogue block re-arms it to 0 at the end of EVERY launch, so graph
// replays always start from 0. It cannot live in d_ws (re-poisoned each iter).
__device__ int g_ctr[BS];

// ---------------------------------------------------------------------------
// fused kernel (r10): attn (r6/r9 body, verified) + per-b last-block epilogue.
// 512 blocks = (b,h), 512 threads. After each block stores its att tile it
// does __threadfence + atomicAdd(g_ctr[b]); the 4th arriver (old==3) runs the
// former epi_kernel for batch b with its 512 threads, overlapping the epilogue
// with the remaining attn blocks and removing the second launch.
// attn math identical to r9 (deterministic compaction, no-max exact softmax,
// reduce-scatter butterfly) -> bit-identical att values.
// ---------------------------------------------------------------------------
__global__ __launch_bounds__(512, 4) void fused_kernel(
    const float* __restrict__ inp, const float* __restrict__ mask,
    const float* __restrict__ Wq, const float* __restrict__ Wk,
    const float* __restrict__ Wv, const float* __restrict__ Wpost,
    float* __restrict__ att_out, float* __restrict__ out)
{
    const int b    = blockIdx.x >> 2;
    const int h    = blockIdx.x & 3;
    const int t    = threadIdx.x;
    const int c    = t & 7;
    const int g    = t >> 3;
    const int w    = t >> 6;
    const int lane = t & 63;

    __shared__ float4 sk[CH * CPAD];
    __shared__ float4 sv[CH * CPAD];
    __shared__ float4 sq[576];            // row-slot s at sq[9*(s>>3) + (s&7)]
    __shared__ unsigned short rlist[512]; // compacted slot -> entity id
    __shared__ int wcnt[8];               // per-wave active counts
    __shared__ float swp[F * NEMBD];      // epilogue: Wpost stage
    __shared__ float red[64];             // epilogue: reduction scratch
    __shared__ int s_old;                 // epilogue: arrival broadcast

    // ---- zero pass: thread t zeroes slot-position t in sk/sv/sq ----
    const float4 z4 = make_float4(0.f, 0.f, 0.f, 0.f);
    sk[c * CPAD + g] = z4;
    sv[c * CPAD + g] = z4;
    sq[9 * g + c]    = z4;

    const float me = mask[b * NE + t];
    const bool act = me > 0.f;            // mask is exactly 0.0 or 1.0

    // ---- deterministic compaction index (ballot + wave-count scan) ----
    const unsigned long long ball = __ballot(act);
    const int prefix = __builtin_amdgcn_mbcnt_hi((unsigned int)(ball >> 32),
                        __builtin_amdgcn_mbcnt_lo((unsigned int)ball, 0));
    if (lane == 0) wcnt[w] = (int)__popcll(ball);

    __syncthreads();   // B1: zeros + wcnt visible

    int base = 0, Nk = 0;
    #pragma unroll
    for (int u = 0; u < 8; ++u) {
        const int cu = wcnt[u];
        Nk += cu;
        if (u < w) base += cu;
    }
    const int L = (Nk + 7) >> 3;              // keys per chunk
    const float lcorr = (float)(8 * L - Nk);  // zero-pad slots give e=1

    // ---- staging: active thread computes K/V/Q for its entity -> slot s ----
    if (act) {
        const int s = base + prefix;
        const float2* rp = (const float2*)(inp + ((size_t)(b * NE + t)) * F);
        const float2 r0 = rp[0], r1 = rp[1], r2 = rp[2];
        const float x0 = r0.x, x1 = r0.y, x2 = r1.x,
                    x3 = r1.y, x4 = r2.x, x5 = r2.y;   // mask=1: no scaling
        const float* wk = Wk + h * DPH * F;
        const float* wv = Wv + h * DPH * F;
        const float* wq = Wq + h * DPH * F;
        const float QS = 0.5f * 1.44269504088896340736f;  // 1/sqrt(4)*log2(e)
        float kk[4], vv[4], qq[4];
        #pragma unroll
        for (int d = 0; d < DPH; ++d) {
            const float* wd = wk + d * F;
            kk[d] = x0*wd[0] + x1*wd[1] + x2*wd[2] + x3*wd[3] + x4*wd[4] + x5*wd[5];
            wd = wv + d * F;
            vv[d] = x0*wd[0] + x1*wd[1] + x2*wd[2] + x3*wd[3] + x4*wd[4] + x5*wd[5];
            wd = wq + d * F;
            qq[d] = QS * (x0*wd[0] + x1*wd[1] + x2*wd[2] + x3*wd[3] + x4*wd[4] + x5*wd[5]);
        }
        sk[(s & 7) * CPAD + (s >> 3)] = make_float4(kk[0], kk[1], kk[2], kk[3]);
        sv[(s & 7) * CPAD + (s >> 3)] = make_float4(vv[0], vv[1], vv[2], vv[3]);
        sq[9 * (s >> 3) + (s & 7)]    = make_float4(qq[0], qq[1], qq[2], qq[3]);
        rlist[s] = (unsigned short)t;
    }

    __syncthreads();   // B2: sk/sv/sq/rlist visible

    // ---- wave-granular row skip: wave w owns row-slots [64w, 64w+64) ----
    // (no early return anymore: all threads must reach the epilogue handoff)
    if (64 * w < Nk) {
        // ---- load q for row-slots 8g..8g+7 (broadcast b128, conflict-free) ----
        float4 qa[8];
        #pragma unroll
        for (int r = 0; r < 8; ++r) qa[r] = sq[9 * g + r];
        v2f qv[4][DPH];
        #pragma unroll
        for (int p = 0; p < 4; ++p) {
            qv[p][0] = (v2f){qa[2*p].x, qa[2*p+1].x};
            qv[p][1] = (v2f){qa[2*p].y, qa[2*p+1].y};
            qv[p][2] = (v2f){qa[2*p].z, qa[2*p+1].z};
            qv[p][3] = (v2f){qa[2*p].w, qa[2*p+1].w};
        }

        // ---- inner loop: L keys of chunk c x 4 packed row pairs ----
        const float4* kb = sk + c * CPAD;
        const float4* vb = sv + c * CPAD;
        v2f l2[4], a2[4][DPH];
        #pragma unroll
        for (int p = 0; p < 4; ++p) {
            l2[p] = (v2f)(0.f);
            #pragma unroll
            for (int d = 0; d < DPH; ++d) a2[p][d] = (v2f)(0.f);
        }

        #pragma unroll 4
        for (int j = 0; j < L; ++j) {
            const float4 kv = kb[j];
            const float4 uv = vb[j];
            const v2f kx = (v2f){kv.x, kv.x}, ky = (v2f){kv.y, kv.y},
                      kz = (v2f){kv.z, kv.z}, kw = (v2f){kv.w, kv.w};
            const v2f ux = (v2f){uv.x, uv.x}, uy = (v2f){uv.y, uv.y},
                      uz = (v2f){uv.z, uv.z}, uw = (v2f){uv.w, uv.w};
            #pragma unroll
            for (int p = 0; p < 4; ++p) {
                v2f s = qv[p][3] * kw;
                s = __builtin_elementwise_fma(qv[p][2], kz, s);
                s = __builtin_elementwise_fma(qv[p][1], ky, s);
                s = __builtin_elementwise_fma(qv[p][0], kx, s);
                v2f e;
                e.x = EXP2(s.x);
                e.y = EXP2(s.y);
                l2[p] += e;
                a2[p][0] = __builtin_elementwise_fma(e, ux, a2[p][0]);
                a2[p][1] = __builtin_elementwise_fma(e, uy, a2[p][1]);
                a2[p][2] = __builtin_elementwise_fma(e, uz, a2[p][2]);
                a2[p][3] = __builtin_elementwise_fma(e, uw, a2[p][3]);
            }
        }

        // ---- reduce-scatter butterfly over the c-octet ---------------------
        const int b0 = c & 1, b1 = (c >> 1) & 1, b2 = (c >> 2) & 1;

        float k1[5][4];   // [val: 0=l, 1..4=a[d]][pair p] -> row 2p + b0
        #pragma unroll
        for (int p = 0; p < 4; ++p) {
            {
                const v2f v = l2[p];
                const float snd = b0 ? v.x : v.y;
                k1[0][p] = (b0 ? v.y : v.x) + __shfl_xor(snd, 1);
            }
            #pragma unroll
            for (int d = 0; d < DPH; ++d) {
                const v2f v = a2[p][d];
                const float snd = b0 ? v.x : v.y;
                k1[1 + d][p] = (b0 ? v.y : v.x) + __shfl_xor(snd, 1);
            }
        }

        float k2[5][2];
        #pragma unroll
        for (int v = 0; v < 5; ++v) {
            #pragma unroll
            for (int q = 0; q < 2; ++q) {
                const float keep = b1 ? k1[v][2*q + 1] : k1[v][2*q];
                const float snd  = b1 ? k1[v][2*q]     : k1[v][2*q + 1];
                k2[v][q] = keep + __shfl_xor(snd, 2);
            }
        }

        float fin[5];
        #pragma unroll
        for (int v = 0; v < 5; ++v) {
            const float keep = b2 ? k2[v][1] : k2[v][0];
            const float snd  = b2 ? k2[v][0] : k2[v][1];
            fin[v] = keep + __shfl_xor(snd, 4);
        }

        const int slot = 8 * g + c;
        if (slot < Nk) {
            const int row = rlist[slot];          // active row: mask = 1
            const float rs = 1.0f / (fin[0] - lcorr);
            float4* o = (float4*)(att_out + ((size_t)(b * NE + row)) * NEMBD + h * DPH);
            *o = make_float4(fin[1] * rs, fin[2] * rs, fin[3] * rs, fin[4] * rs);
        }
    }

    // ---- epilogue handoff: 4th (b,*) block to arrive runs the epilogue ----
    __syncthreads();   // B3: all this block's att stores drained (vmcnt0 at barrier)
    if (t == 0) {
        __threadfence();                        // release att tile, device scope
        s_old = atomicAdd(&g_ctr[b], 1);
    }
    __syncthreads();   // B4: s_old visible
    if (s_old != NH - 1) return;
    __threadfence();                            // acquire: see other blocks' att

    // ---- epilogue (former epi_kernel, i := t, 512 threads, one block/b) ----
    if (t < F * NEMBD) swp[t] = Wpost[t];
    __syncthreads();

    const float mi = me;                        // same entity t of batch b
    const float* row = inp + ((size_t)(b * NE + t)) * F;
    const float* ar  = att_out + ((size_t)(b * NE + t)) * NEMBD;

    float a[NEMBD];
    #pragma unroll
    for (int u = 0; u < NEMBD; u += 4) {
        const float4 v = *(const float4*)(ar + u);
        a[u] = v.x * mi; a[u+1] = v.y * mi; a[u+2] = v.z * mi; a[u+3] = v.w * mi;
    }

    float x[F];
    #pragma unroll
    for (int f = 0; f < F; ++f) {
        float acc = row[f] * mi;
        #pragma unroll
        for (int u = 0; u < NEMBD; ++u) acc = fmaf(a[u], swp[f * NEMBD + u], acc);
        x[f] = acc;
    }

    // ---- phase 1: S = sum(x), N = sum(mask) ----
    float rsum = x[0] + x[1] + x[2] + x[3] + x[4] + x[5];
    float rn = mi;
    #pragma unroll
    for (int off = 32; off >= 1; off >>= 1) {
        rsum += __shfl_down(rsum, off);
        rn   += __shfl_down(rn, off);
    }
    if (lane == 0) { red[w * 2] = rsum; red[w * 2 + 1] = rn; }
    __syncthreads();
    float S = 0.f, N = 0.f;
    #pragma unroll
    for (int u = 0; u < 8; ++u) { S += red[u * 2]; N += red[u * 2 + 1]; }

    const float mu     = S / (6.0f * N);
    const float sum_x2 = S + (NE - N) * 6.0f * mu;
    const float m2     = sum_x2 / (NE * 6.0f);
    const float add    = (1.0f - mi) * mu;

    float ss = 0.f;
    #pragma unroll
    for (int f = 0; f < F; ++f) { const float d = x[f] + add - m2; ss = fmaf(d, d, ss); }

    // ---- phase 2: sum of squares ----
    __syncthreads();
    #pragma unroll
    for (int off = 32; off >= 1; off >>= 1) ss += __shfl_down(ss, off);
    if (lane == 0) red[w] = ss;
    __syncthreads();
    float vs = 0.f;
    #pragma unroll
    for (int u = 0; u < 8; ++u) vs += red[u];

    const float var  = vs / (NE * 6.0f - 1.0f);
    const float stdv = sqrtf(var) * sqrtf((6.0f * NE - 1.0f) / (6.0f * N - 1.0f));
    const float inv  = 1.0f / (stdv + 1e-6f);

    float y[F];
    #pragma unroll
    for (int f = 0; f < F; ++f) y[f] = mi * (x[f] - mu) * inv;

    // ---- phase 3: 6 masked feature sums ----
    __syncthreads();
    #pragma unroll
    for (int off = 32; off >= 1; off >>= 1) {
        #pragma unroll
        for (int f = 0; f < F; ++f) y[f] += __shfl_down(y[f], off);
    }
    if (lane == 0) {
        #pragma unroll
        for (int f = 0; f < F; ++f) red[w * F + f] = y[f];
    }
    __syncthreads();
    if (t < F) {
        float tt = 0.f;
        #pragma unroll
        for (int u = 0; u < 8; ++u) tt += red[u * F + t];
        out[b * F + t] = tt / N;
    }

    // ---- re-arm the counter for the next (graph-replayed) launch ----
    if (t == 0) atomicExch(&g_ctr[b], 0);
}

// ---------------------------------------------------------------------------
extern "C" void kernel_launch(void* const* d_in, const int* in_sizes, int n_in,
                              void* d_out, int out_size, void* d_ws, size_t ws_size,
                              hipStream_t stream) {
    const float* inp   = (const float*)d_in[0];
    const float* mask  = (const float*)d_in[1];
    const float* Wq    = (const float*)d_in[2];
    const float* Wk    = (const float*)d_in[3];
    const float* Wv    = (const float*)d_in[4];
    const float* Wpost = (const float*)d_in[5];
    float* out = (float*)d_out;
    float* att = (float*)d_ws;   // BS*NE*NEMBD floats = 4 MB

    fused_kernel<<<BS * NH, 512, 0, stream>>>(inp, mask, Wq, Wk, Wv, Wpost, att, out);
}

// Round 3
// 109.206 us; speedup vs baseline: 1.3273x; 1.3273x over previous
//
#include <hip/hip_runtime.h>
#include <math.h>

#define BS    128
#define NE    512
#define F     6
#define NH    4
#define DPH   4
#define NEMBD 16

#define CH    8
#define CPAD  65   // float4 stride per chunk; 8 broadcast addrs/wave, conflict-free (r2-r8)

#if __has_builtin(__builtin_amdgcn_exp2f)
#define EXP2(x) __builtin_amdgcn_exp2f(x)
#else
#define EXP2(x) exp2f(x)
#endif

typedef float v2f __attribute__((ext_vector_type(2)));
typedef unsigned long long u64;

// Per-batch arrival counter for the fused epilogue. Zero-initialized at module
// load; the epilogue block re-arms it to 0 at the end of EVERY launch, so graph
// replays always start from 0. Cannot live in d_ws (re-poisoned each iter).
__device__ int g_ctr[BS];

// ---------------------------------------------------------------------------
// fused kernel (r12 = r11 + hardened handoff): attn (r6/r9 body, verified) +
// per-b last-block epilogue.
// r10 post-mortem: __launch_bounds__(512,4) clamped VGPR to 64 -> inner-loop
// spills (+8 MB scratch writes, VALUBusy 17%, 115-134 us). r11 fixed that but
// never ran (container infra failure). r12 changes vs r11:
//   * arrival counter uses __hip_atomic_fetch_add(ACQ_REL, AGENT scope) --
//     the release orders this block's att stores before the increment, the
//     acquire in the last arriver makes all 4 blocks' stores visible. This is
//     the architecturally-defined cross-XCD producer/consumer protocol; LLVM
//     emits the exact waitcnt/cache-op sequence (no hand-rolled fences).
//   * att tile additionally stored/loaded with per-access coherence bits
//     (system-scope relaxed atomics -> sc0 sc1; write-through, no bulk L2
//     flush) as a second line of defense. Cost ~0 (4 MB must be written
//     anyway; epilogue reads 256 KB total).
// attn math identical to r9 -> bit-identical att values.
// ---------------------------------------------------------------------------
__global__ __launch_bounds__(512) void fused_kernel(
    const float* __restrict__ inp, const float* __restrict__ mask,
    const float* __restrict__ Wq, const float* __restrict__ Wk,
    const float* __restrict__ Wv, const float* __restrict__ Wpost,
    float* __restrict__ att_out, float* __restrict__ out)
{
    const int b    = blockIdx.x >> 2;
    const int h    = blockIdx.x & 3;
    const int t    = threadIdx.x;
    const int c    = t & 7;
    const int g    = t >> 3;
    const int w    = t >> 6;
    const int lane = t & 63;

    __shared__ float4 sk[CH * CPAD];
    __shared__ float4 sv[CH * CPAD];
    __shared__ float4 sq[576];            // row-slot s at sq[9*(s>>3) + (s&7)]
    __shared__ unsigned short rlist[512]; // compacted slot -> entity id
    __shared__ int wcnt[8];               // per-wave active counts
    __shared__ float swp[F * NEMBD];      // epilogue: Wpost stage
    __shared__ float red[64];             // epilogue: reduction scratch
    __shared__ int s_old;                 // epilogue: arrival broadcast

    // ---- zero pass: thread t zeroes slot-position t in sk/sv/sq ----
    const float4 z4 = make_float4(0.f, 0.f, 0.f, 0.f);
    sk[c * CPAD + g] = z4;
    sv[c * CPAD + g] = z4;
    sq[9 * g + c]    = z4;

    const float me = mask[b * NE + t];
    const bool act = me > 0.f;            // mask is exactly 0.0 or 1.0

    // ---- deterministic compaction index (ballot + wave-count scan) ----
    const unsigned long long ball = __ballot(act);
    const int prefix = __builtin_amdgcn_mbcnt_hi((unsigned int)(ball >> 32),
                        __builtin_amdgcn_mbcnt_lo((unsigned int)ball, 0));
    if (lane == 0) wcnt[w] = (int)__popcll(ball);

    __syncthreads();   // B1: zeros + wcnt visible

    int base = 0, Nk = 0;
    #pragma unroll
    for (int u = 0; u < 8; ++u) {
        const int cu = wcnt[u];
        Nk += cu;
        if (u < w) base += cu;
    }
    const int L = (Nk + 7) >> 3;              // keys per chunk
    const float lcorr = (float)(8 * L - Nk);  // zero-pad slots give e=1

    // ---- staging: active thread computes K/V/Q for its entity -> slot s ----
    if (act) {
        const int s = base + prefix;
        const float2* rp = (const float2*)(inp + ((size_t)(b * NE + t)) * F);
        const float2 r0 = rp[0], r1 = rp[1], r2 = rp[2];
        const float x0 = r0.x, x1 = r0.y, x2 = r1.x,
                    x3 = r1.y, x4 = r2.x, x5 = r2.y;   // mask=1: no scaling
        const float* wk = Wk + h * DPH * F;
        const float* wv = Wv + h * DPH * F;
        const float* wq = Wq + h * DPH * F;
        const float QS = 0.5f * 1.44269504088896340736f;  // 1/sqrt(4)*log2(e)
        float kk[4], vv[4], qq[4];
        #pragma unroll
        for (int d = 0; d < DPH; ++d) {
            const float* wd = wk + d * F;
            kk[d] = x0*wd[0] + x1*wd[1] + x2*wd[2] + x3*wd[3] + x4*wd[4] + x5*wd[5];
            wd = wv + d * F;
            vv[d] = x0*wd[0] + x1*wd[1] + x2*wd[2] + x3*wd[3] + x4*wd[4] + x5*wd[5];
            wd = wq + d * F;
            qq[d] = QS * (x0*wd[0] + x1*wd[1] + x2*wd[2] + x3*wd[3] + x4*wd[4] + x5*wd[5]);
        }
        sk[(s & 7) * CPAD + (s >> 3)] = make_float4(kk[0], kk[1], kk[2], kk[3]);
        sv[(s & 7) * CPAD + (s >> 3)] = make_float4(vv[0], vv[1], vv[2], vv[3]);
        sq[9 * (s >> 3) + (s & 7)]    = make_float4(qq[0], qq[1], qq[2], qq[3]);
        rlist[s] = (unsigned short)t;
    }

    __syncthreads();   // B2: sk/sv/sq/rlist visible

    // ---- wave-granular row skip: wave w owns row-slots [64w, 64w+64) ----
    // (no early return: all threads must reach the epilogue handoff)
    if (64 * w < Nk) {
        // ---- load q for row-slots 8g..8g+7 (broadcast b128, conflict-free) ----
        float4 qa[8];
        #pragma unroll
        for (int r = 0; r < 8; ++r) qa[r] = sq[9 * g + r];
        v2f qv[4][DPH];
        #pragma unroll
        for (int p = 0; p < 4; ++p) {
            qv[p][0] = (v2f){qa[2*p].x, qa[2*p+1].x};
            qv[p][1] = (v2f){qa[2*p].y, qa[2*p+1].y};
            qv[p][2] = (v2f){qa[2*p].z, qa[2*p+1].z};
            qv[p][3] = (v2f){qa[2*p].w, qa[2*p+1].w};
        }

        // ---- inner loop: L keys of chunk c x 4 packed row pairs ----
        const float4* kb = sk + c * CPAD;
        const float4* vb = sv + c * CPAD;
        v2f l2[4], a2[4][DPH];
        #pragma unroll
        for (int p = 0; p < 4; ++p) {
            l2[p] = (v2f)(0.f);
            #pragma unroll
            for (int d = 0; d < DPH; ++d) a2[p][d] = (v2f)(0.f);
        }

        #pragma unroll 4
        for (int j = 0; j < L; ++j) {
            const float4 kv = kb[j];
            const float4 uv = vb[j];
            const v2f kx = (v2f){kv.x, kv.x}, ky = (v2f){kv.y, kv.y},
                      kz = (v2f){kv.z, kv.z}, kw = (v2f){kv.w, kv.w};
            const v2f ux = (v2f){uv.x, uv.x}, uy = (v2f){uv.y, uv.y},
                      uz = (v2f){uv.z, uv.z}, uw = (v2f){uv.w, uv.w};
            #pragma unroll
            for (int p = 0; p < 4; ++p) {
                v2f s = qv[p][3] * kw;
                s = __builtin_elementwise_fma(qv[p][2], kz, s);
                s = __builtin_elementwise_fma(qv[p][1], ky, s);
                s = __builtin_elementwise_fma(qv[p][0], kx, s);
                v2f e;
                e.x = EXP2(s.x);
                e.y = EXP2(s.y);
                l2[p] += e;
                a2[p][0] = __builtin_elementwise_fma(e, ux, a2[p][0]);
                a2[p][1] = __builtin_elementwise_fma(e, uy, a2[p][1]);
                a2[p][2] = __builtin_elementwise_fma(e, uz, a2[p][2]);
                a2[p][3] = __builtin_elementwise_fma(e, uw, a2[p][3]);
            }
        }

        // ---- reduce-scatter butterfly over the c-octet ---------------------
        const int b0 = c & 1, b1 = (c >> 1) & 1, b2 = (c >> 2) & 1;

        float k1[5][4];   // [val: 0=l, 1..4=a[d]][pair p] -> row 2p + b0
        #pragma unroll
        for (int p = 0; p < 4; ++p) {
            {
                const v2f v = l2[p];
                const float snd = b0 ? v.x : v.y;
                k1[0][p] = (b0 ? v.y : v.x) + __shfl_xor(snd, 1);
            }
            #pragma unroll
            for (int d = 0; d < DPH; ++d) {
                const v2f v = a2[p][d];
                const float snd = b0 ? v.x : v.y;
                k1[1 + d][p] = (b0 ? v.y : v.x) + __shfl_xor(snd, 1);
            }
        }

        float k2[5][2];
        #pragma unroll
        for (int v = 0; v < 5; ++v) {
            #pragma unroll
            for (int q = 0; q < 2; ++q) {
                const float keep = b1 ? k1[v][2*q + 1] : k1[v][2*q];
                const float snd  = b1 ? k1[v][2*q]     : k1[v][2*q + 1];
                k2[v][q] = keep + __shfl_xor(snd, 2);
            }
        }

        float fin[5];
        #pragma unroll
        for (int v = 0; v < 5; ++v) {
            const float keep = b2 ? k2[v][1] : k2[v][0];
            const float snd  = b2 ? k2[v][0] : k2[v][1];
            fin[v] = keep + __shfl_xor(snd, 4);
        }

        const int slot = 8 * g + c;
        if (slot < Nk) {
            const int row = rlist[slot];          // active row: mask = 1
            const float rs = 1.0f / (fin[0] - lcorr);
            // per-access coherence (sc0 sc1): write-through to the coherent
            // point; no bulk L2 maintenance needed for cross-block visibility
            u64* o = (u64*)(att_out + ((size_t)(b * NE + row)) * NEMBD + h * DPH);
            union { float f[2]; u64 u8; } p0, p1;
            p0.f[0] = fin[1] * rs; p0.f[1] = fin[2] * rs;
            p1.f[0] = fin[3] * rs; p1.f[1] = fin[4] * rs;
            __hip_atomic_store(o,     p0.u8, __ATOMIC_RELAXED, __HIP_MEMORY_SCOPE_SYSTEM);
            __hip_atomic_store(o + 1, p1.u8, __ATOMIC_RELAXED, __HIP_MEMORY_SCOPE_SYSTEM);
        }
    }

    // ---- epilogue handoff: 4th (b,*) block to arrive runs the epilogue ----
    __syncthreads();   // B3: all waves of this block done storing att
    if (t == 0) {
        // release: order this block's att stores before the increment;
        // acquire (in the observer of old==3): make all blocks' stores visible
        s_old = __hip_atomic_fetch_add(&g_ctr[b], 1,
                                       __ATOMIC_ACQ_REL, __HIP_MEMORY_SCOPE_AGENT);
    }
    __syncthreads();   // B4: s_old visible
    if (s_old != NH - 1) return;

    // ---- epilogue (former epi_kernel, i := t, 512 threads, one block/b) ----
    if (t < F * NEMBD) swp[t] = Wpost[t];
    __syncthreads();

    const float mi = me;                        // same entity t of batch b
    const float* row = inp + ((size_t)(b * NE + t)) * F;

    // att loads with per-access coherence bits (sc0 sc1): read the coherent
    // point, never a stale per-XCD L2 line.
    float a[NEMBD];
    const u64* ap = (const u64*)(att_out + ((size_t)(b * NE + t)) * NEMBD);
    #pragma unroll
    for (int u = 0; u < NEMBD / 2; ++u) {
        union { u64 u8; float f[2]; } cv;
        cv.u8 = __hip_atomic_load(ap + u, __ATOMIC_RELAXED, __HIP_MEMORY_SCOPE_SYSTEM);
        a[2*u]   = cv.f[0] * mi;
        a[2*u+1] = cv.f[1] * mi;
    }

    float x[F];
    #pragma unroll
    for (int f = 0; f < F; ++f) {
        float acc = row[f] * mi;
        #pragma unroll
        for (int u = 0; u < NEMBD; ++u) acc = fmaf(a[u], swp[f * NEMBD + u], acc);
        x[f] = acc;
    }

    // ---- phase 1: S = sum(x), N = sum(mask) ----
    float rsum = x[0] + x[1] + x[2] + x[3] + x[4] + x[5];
    float rn = mi;
    #pragma unroll
    for (int off = 32; off >= 1; off >>= 1) {
        rsum += __shfl_down(rsum, off);
        rn   += __shfl_down(rn, off);
    }
    if (lane == 0) { red[w * 2] = rsum; red[w * 2 + 1] = rn; }
    __syncthreads();
    float S = 0.f, N = 0.f;
    #pragma unroll
    for (int u = 0; u < 8; ++u) { S += red[u * 2]; N += red[u * 2 + 1]; }

    const float mu     = S / (6.0f * N);
    const float sum_x2 = S + (NE - N) * 6.0f * mu;
    const float m2     = sum_x2 / (NE * 6.0f);
    const float add    = (1.0f - mi) * mu;

    float ss = 0.f;
    #pragma unroll
    for (int f = 0; f < F; ++f) { const float d = x[f] + add - m2; ss = fmaf(d, d, ss); }

    // ---- phase 2: sum of squares ----
    __syncthreads();
    #pragma unroll
    for (int off = 32; off >= 1; off >>= 1) ss += __shfl_down(ss, off);
    if (lane == 0) red[w] = ss;
    __syncthreads();
    float vs = 0.f;
    #pragma unroll
    for (int u = 0; u < 8; ++u) vs += red[u];

    const float var  = vs / (NE * 6.0f - 1.0f);
    const float stdv = sqrtf(var) * sqrtf((6.0f * NE - 1.0f) / (6.0f * N - 1.0f));
    const float inv  = 1.0f / (stdv + 1e-6f);

    float y[F];
    #pragma unroll
    for (int f = 0; f < F; ++f) y[f] = mi * (x[f] - mu) * inv;

    // ---- phase 3: 6 masked feature sums ----
    __syncthreads();
    #pragma unroll
    for (int off = 32; off >= 1; off >>= 1) {
        #pragma unroll
        for (int f = 0; f < F; ++f) y[f] += __shfl_down(y[f], off);
    }
    if (lane == 0) {
        #pragma unroll
        for (int f = 0; f < F; ++f) red[w * F + f] = y[f];
    }
    __syncthreads();
    if (t < F) {
        float tt = 0.f;
        #pragma unroll
        for (int u = 0; u < 8; ++u) tt += red[u * F + t];
        out[b * F + t] = tt / N;
    }

    // ---- re-arm the counter for the next (graph-replayed) launch ----
    if (t == 0)
        __hip_atomic_store(&g_ctr[b], 0, __ATOMIC_RELAXED, __HIP_MEMORY_SCOPE_AGENT);
}

// ---------------------------------------------------------------------------
extern "C" void kernel_launch(void* const* d_in, const int* in_sizes, int n_in,
                              void* d_out, int out_size, void* d_ws, size_t ws_size,
                              hipStream_t stream) {
    const float* inp   = (const float*)d_in[0];
    const float* mask  = (const float*)d_in[1];
    const float* Wq    = (const float*)d_in[2];
    const float* Wk    = (const float*)d_in[3];
    const float* Wv    = (const float*)d_in[4];
    const float* Wpost = (const float*)d_in[5];
    float* out = (float*)d_out;
    float* att = (float*)d_ws;   // BS*NE*NEMBD floats = 4 MB

    fused_kernel<<<BS * NH, 512, 0, stream>>>(inp, mask, Wq, Wk, Wv, Wpost, att, out);
}

// Round 4
// 94.099 us; speedup vs baseline: 1.5404x; 1.1605x over previous
//
#include <hip/hip_runtime.h>
#include <math.h>

#define BS    128
#define NE    512
#define F     6
#define NH    4
#define DPH   4
#define NEMBD 16

#define CH    8
#define CPAD  65   // float4 stride per chunk; 8 broadcast addrs/wave, conflict-free (r2-r8)

#if __has_builtin(__builtin_amdgcn_exp2f)
#define EXP2(x) __builtin_amdgcn_exp2f(x)
#else
#define EXP2(x) exp2f(x)
#endif

typedef float v2f __attribute__((ext_vector_type(2)));

// ---------------------------------------------------------------------------
// attention (r13 = r9 two-kernel revert + VGPR budget fix).
// r10-r12 fusion post-mortem: last-block epilogue tail (128 blocks, 12.5%
// occupancy, uncached system-scope loads) + per-block acquire L2-invalidates
// cost far more than the launch gap they saved. Reverted.
// KEY r12 diagnostic kept: with LDS=27648B the backend's occupancy heuristic
// (5 blocks/CU -> 8 waves/SIMD target) budgets ~64-68 VGPRs, but the inner
// loop holds ~72 VGPRs of accumulators (qv 32 + a2 32 + l2 8) + operands ->
// setup spills (~9 MB scratch writes seen in r12). Fix: __launch_bounds__
// (512, 2): min 2 waves/EU -> VGPR cap 256; compiler allocates the ~110-130
// it needs; at <=128 VGPR hardware still co-schedules 4 waves/EU = 2
// blocks/CU = exactly the work per CU (512 blocks / 256 CUs).
// attn math identical to r9 -> bit-identical output.
// ---------------------------------------------------------------------------
__global__ __launch_bounds__(512, 2) void attn_kernel(
    const float* __restrict__ inp, const float* __restrict__ mask,
    const float* __restrict__ Wq, const float* __restrict__ Wk,
    const float* __restrict__ Wv, float* __restrict__ att_out)
{
    const int b    = blockIdx.x >> 2;
    const int h    = blockIdx.x & 3;
    const int t    = threadIdx.x;
    const int c    = t & 7;
    const int g    = t >> 3;
    const int w    = t >> 6;
    const int lane = t & 63;

    __shared__ float4 sk[CH * CPAD];
    __shared__ float4 sv[CH * CPAD];
    __shared__ float4 sq[576];            // row-slot s at sq[9*(s>>3) + (s&7)]
    __shared__ unsigned short rlist[512]; // compacted slot -> entity id
    __shared__ int wcnt[8];               // per-wave active counts

    // ---- zero pass: thread t zeroes slot-position t in sk/sv/sq ----
    const float4 z4 = make_float4(0.f, 0.f, 0.f, 0.f);
    sk[c * CPAD + g] = z4;
    sv[c * CPAD + g] = z4;
    sq[9 * g + c]    = z4;

    const float me = mask[b * NE + t];
    const bool act = me > 0.f;            // mask is exactly 0.0 or 1.0

    // ---- deterministic compaction index (ballot + wave-count scan) ----
    const unsigned long long ball = __ballot(act);
    const int prefix = __builtin_amdgcn_mbcnt_hi((unsigned int)(ball >> 32),
                        __builtin_amdgcn_mbcnt_lo((unsigned int)ball, 0));
    if (lane == 0) wcnt[w] = (int)__popcll(ball);

    __syncthreads();   // B1: zeros + wcnt visible

    int base = 0, Nk = 0;
    #pragma unroll
    for (int u = 0; u < 8; ++u) {
        const int cu = wcnt[u];
        Nk += cu;
        if (u < w) base += cu;
    }
    const int L = (Nk + 7) >> 3;              // keys per chunk
    const float lcorr = (float)(8 * L - Nk);  // zero-pad slots give e=1

    // ---- staging: active thread computes K/V/Q for its entity -> slot s ----
    if (act) {
        const int s = base + prefix;
        const float2* rp = (const float2*)(inp + ((size_t)(b * NE + t)) * F);
        const float2 r0 = rp[0], r1 = rp[1], r2 = rp[2];
        const float x0 = r0.x, x1 = r0.y, x2 = r1.x,
                    x3 = r1.y, x4 = r2.x, x5 = r2.y;   // mask=1: no scaling
        const float* wk = Wk + h * DPH * F;
        const float* wv = Wv + h * DPH * F;
        const float* wq = Wq + h * DPH * F;
        const float QS = 0.5f * 1.44269504088896340736f;  // 1/sqrt(4)*log2(e)
        float kk[4], vv[4], qq[4];
        #pragma unroll
        for (int d = 0; d < DPH; ++d) {
            const float* wd = wk + d * F;
            kk[d] = x0*wd[0] + x1*wd[1] + x2*wd[2] + x3*wd[3] + x4*wd[4] + x5*wd[5];
            wd = wv + d * F;
            vv[d] = x0*wd[0] + x1*wd[1] + x2*wd[2] + x3*wd[3] + x4*wd[4] + x5*wd[5];
            wd = wq + d * F;
            qq[d] = QS * (x0*wd[0] + x1*wd[1] + x2*wd[2] + x3*wd[3] + x4*wd[4] + x5*wd[5]);
        }
        sk[(s & 7) * CPAD + (s >> 3)] = make_float4(kk[0], kk[1], kk[2], kk[3]);
        sv[(s & 7) * CPAD + (s >> 3)] = make_float4(vv[0], vv[1], vv[2], vv[3]);
        sq[9 * (s >> 3) + (s & 7)]    = make_float4(qq[0], qq[1], qq[2], qq[3]);
        rlist[s] = (unsigned short)t;
    }

    __syncthreads();   // B2: sk/sv/sq/rlist visible

    // ---- wave-granular row skip: wave w owns row-slots [64w, 64w+64) ----
    if (64 * w >= Nk) return;

    // ---- load q for row-slots 8g..8g+7 (broadcast b128, conflict-free) ----
    float4 qa[8];
    #pragma unroll
    for (int r = 0; r < 8; ++r) qa[r] = sq[9 * g + r];
    v2f qv[4][DPH];
    #pragma unroll
    for (int p = 0; p < 4; ++p) {
        qv[p][0] = (v2f){qa[2*p].x, qa[2*p+1].x};
        qv[p][1] = (v2f){qa[2*p].y, qa[2*p+1].y};
        qv[p][2] = (v2f){qa[2*p].z, qa[2*p+1].z};
        qv[p][3] = (v2f){qa[2*p].w, qa[2*p+1].w};
    }

    // ---- inner loop: L keys of chunk c x 4 packed row pairs ----
    const float4* kb = sk + c * CPAD;
    const float4* vb = sv + c * CPAD;
    v2f l2[4], a2[4][DPH];
    #pragma unroll
    for (int p = 0; p < 4; ++p) {
        l2[p] = (v2f)(0.f);
        #pragma unroll
        for (int d = 0; d < DPH; ++d) a2[p][d] = (v2f)(0.f);
    }

    #pragma unroll 4
    for (int j = 0; j < L; ++j) {
        const float4 kv = kb[j];
        const float4 uv = vb[j];
        const v2f kx = (v2f){kv.x, kv.x}, ky = (v2f){kv.y, kv.y},
                  kz = (v2f){kv.z, kv.z}, kw = (v2f){kv.w, kv.w};
        const v2f ux = (v2f){uv.x, uv.x}, uy = (v2f){uv.y, uv.y},
                  uz = (v2f){uv.z, uv.z}, uw = (v2f){uv.w, uv.w};
        #pragma unroll
        for (int p = 0; p < 4; ++p) {
            v2f s = qv[p][3] * kw;
            s = __builtin_elementwise_fma(qv[p][2], kz, s);
            s = __builtin_elementwise_fma(qv[p][1], ky, s);
            s = __builtin_elementwise_fma(qv[p][0], kx, s);
            v2f e;
            e.x = EXP2(s.x);
            e.y = EXP2(s.y);
            l2[p] += e;
            a2[p][0] = __builtin_elementwise_fma(e, ux, a2[p][0]);
            a2[p][1] = __builtin_elementwise_fma(e, uy, a2[p][1]);
            a2[p][2] = __builtin_elementwise_fma(e, uz, a2[p][2]);
            a2[p][3] = __builtin_elementwise_fma(e, uw, a2[p][3]);
        }
    }

    // ---- reduce-scatter butterfly over the c-octet ---------------------
    // step 1 (xor 1): keep row-parity b0 of each pair; partner sends the
    // row I keep. Same pairing tree as the old full butterfly -> identical fp.
    const int b0 = c & 1, b1 = (c >> 1) & 1, b2 = (c >> 2) & 1;

    float k1[5][4];   // [val: 0=l, 1..4=a[d]][pair p] -> row 2p + b0
    #pragma unroll
    for (int p = 0; p < 4; ++p) {
        {
            const v2f v = l2[p];
            const float snd = b0 ? v.x : v.y;
            k1[0][p] = (b0 ? v.y : v.x) + __shfl_xor(snd, 1);
        }
        #pragma unroll
        for (int d = 0; d < DPH; ++d) {
            const v2f v = a2[p][d];
            const float snd = b0 ? v.x : v.y;
            k1[1 + d][p] = (b0 ? v.y : v.x) + __shfl_xor(snd, 1);
        }
    }

    // step 2 (xor 2): keep pairs p with (p&1)==b1 -> rows 4q + 2b1 + b0
    float k2[5][2];
    #pragma unroll
    for (int v = 0; v < 5; ++v) {
        #pragma unroll
        for (int q = 0; q < 2; ++q) {
            const float keep = b1 ? k1[v][2*q + 1] : k1[v][2*q];
            const float snd  = b1 ? k1[v][2*q]     : k1[v][2*q + 1];
            k2[v][q] = keep + __shfl_xor(snd, 2);
        }
    }

    // step 3 (xor 4): keep q==b2 -> final row = 4b2 + 2b1 + b0 = c
    float fin[5];
    #pragma unroll
    for (int v = 0; v < 5; ++v) {
        const float keep = b2 ? k2[v][1] : k2[v][0];
        const float snd  = b2 ? k2[v][0] : k2[v][1];
        fin[v] = keep + __shfl_xor(snd, 4);
    }

    const int slot = 8 * g + c;
    if (slot < Nk) {
        const int row = rlist[slot];          // active row: mask = 1
        const float rs = 1.0f / (fin[0] - lcorr);
        float4* o = (float4*)(att_out + ((size_t)(b * NE + row)) * NEMBD + h * DPH);
        *o = make_float4(fin[1] * rs, fin[2] * rs, fin[3] * rs, fin[4] * rs);
    }
}

// ---------------------------------------------------------------------------
// epilogue: post-proj + residual + mask-corrected norm + masked mean pool.
// att rows of masked entities are never written (poison) -> zeroed via *mi.
// Verified r6-r8. Low register pressure; default budget fits -> no bound tweak.
// ---------------------------------------------------------------------------
__global__ __launch_bounds__(NE) void epi_kernel(
    const float* __restrict__ inp, const float* __restrict__ mask,
    const float* __restrict__ Wpost, const float* __restrict__ att,
    float* __restrict__ out)
{
    const int b = blockIdx.x;
    const int i = threadIdx.x;
    const int wave = i >> 6;
    const int lane = i & 63;

    __shared__ float swp[F * NEMBD];
    __shared__ float red[64];

    if (i < F * NEMBD) swp[i] = Wpost[i];
    __syncthreads();

    const float mi = mask[b * NE + i];
    const float* row = inp + ((size_t)(b * NE + i)) * F;
    const float* ar  = att + ((size_t)(b * NE + i)) * NEMBD;

    float a[NEMBD];
    #pragma unroll
    for (int t = 0; t < NEMBD; t += 4) {
        const float4 v = *(const float4*)(ar + t);
        a[t] = v.x * mi; a[t+1] = v.y * mi; a[t+2] = v.z * mi; a[t+3] = v.w * mi;
    }

    float x[F];
    #pragma unroll
    for (int f = 0; f < F; ++f) {
        float acc = row[f] * mi;
        #pragma unroll
        for (int t = 0; t < NEMBD; ++t) acc = fmaf(a[t], swp[f * NEMBD + t], acc);
        x[f] = acc;
    }

    // ---- phase 1: S = sum(x), N = sum(mask) ----
    float rsum = x[0] + x[1] + x[2] + x[3] + x[4] + x[5];
    float rn = mi;
    #pragma unroll
    for (int off = 32; off >= 1; off >>= 1) {
        rsum += __shfl_down(rsum, off);
        rn   += __shfl_down(rn, off);
    }
    if (lane == 0) { red[wave * 2] = rsum; red[wave * 2 + 1] = rn; }
    __syncthreads();
    float S = 0.f, N = 0.f;
    #pragma unroll
    for (int w = 0; w < 8; ++w) { S += red[w * 2]; N += red[w * 2 + 1]; }

    const float mu     = S / (6.0f * N);
    const float sum_x2 = S + (NE - N) * 6.0f * mu;
    const float m2     = sum_x2 / (NE * 6.0f);
    const float add    = (1.0f - mi) * mu;

    float ss = 0.f;
    #pragma unroll
    for (int f = 0; f < F; ++f) { const float d = x[f] + add - m2; ss = fmaf(d, d, ss); }

    // ---- phase 2: sum of squares ----
    __syncthreads();
    #pragma unroll
    for (int off = 32; off >= 1; off >>= 1) ss += __shfl_down(ss, off);
    if (lane == 0) red[wave] = ss;
    __syncthreads();
    float vs = 0.f;
    #pragma unroll
    for (int w = 0; w < 8; ++w) vs += red[w];

    const float var  = vs / (NE * 6.0f - 1.0f);
    const float stdv = sqrtf(var) * sqrtf((6.0f * NE - 1.0f) / (6.0f * N - 1.0f));
    const float inv  = 1.0f / (stdv + 1e-6f);

    float y[F];
    #pragma unroll
    for (int f = 0; f < F; ++f) y[f] = mi * (x[f] - mu) * inv;

    // ---- phase 3: 6 masked feature sums ----
    __syncthreads();
    #pragma unroll
    for (int off = 32; off >= 1; off >>= 1) {
        #pragma unroll
        for (int f = 0; f < F; ++f) y[f] += __shfl_down(y[f], off);
    }
    if (lane == 0) {
        #pragma unroll
        for (int f = 0; f < F; ++f) red[wave * F + f] = y[f];
    }
    __syncthreads();
    if (i < F) {
        float tt = 0.f;
        #pragma unroll
        for (int w = 0; w < 8; ++w) tt += red[w * F + i];
        out[b * F + i] = tt / N;
    }
}

// ---------------------------------------------------------------------------
extern "C" void kernel_launch(void* const* d_in, const int* in_sizes, int n_in,
                              void* d_out, int out_size, void* d_ws, size_t ws_size,
                              hipStream_t stream) {
    const float* inp   = (const float*)d_in[0];
    const float* mask  = (const float*)d_in[1];
    const float* Wq    = (const float*)d_in[2];
    const float* Wk    = (const float*)d_in[3];
    const float* Wv    = (const float*)d_in[4];
    const float* Wpost = (const float*)d_in[5];
    float* out = (float*)d_out;
    float* att = (float*)d_ws;   // BS*NE*NEMBD floats = 4 MB

    attn_kernel<<<BS * NH, 512, 0, stream>>>(inp, mask, Wq, Wk, Wv, att);
    epi_kernel <<<BS, NE, 0, stream>>>(inp, mask, Wpost, att, out);
}